// Round 4
// baseline (309.739 us; speedup 1.0000x reference)
//
#include <hip/hip_runtime.h>

// PointPillarScatter (B=4, C=64, 512x512x1 grid, P=120000)
// Invert scatter -> gather:
//   1) memset cell->pillar map (d_ws) to -1              (4 MiB)
//   2) scatter: map[b*cells + cell] = p                  (tiny)
//   3) gather: ONE cell per thread. Load the whole 256 B pillar row into
//      registers (16 consecutive fv4 loads -> full cache-line consumption,
//      no L1/L2 re-fetch), then 64 coalesced nontemporal dword stores
//      (256 B per wave per instruction = two full 128 B lines).

#define G_NX 512
#define G_NY 512
#define G_C 64
#define G_B 4
#define G_CELLS (G_NX * G_NY) // 262144 (nz == 1)

typedef float fv4 __attribute__((ext_vector_type(4)));

__global__ __launch_bounds__(256) void ppscatter_map_kernel(
    const int* __restrict__ coords, int* __restrict__ map, int P) {
  int p = blockIdx.x * blockDim.x + threadIdx.x;
  if (p >= P) return;
  int4 cr = ((const int4*)coords)[p]; // [b, z, y, x]
  map[cr.x * G_CELLS + (cr.y + cr.z * G_NX + cr.w)] = p;
}

// grid: (CELLS/256, B), block 256. Thread owns ONE cell.
__global__ __launch_bounds__(256) void ppscatter_gather_kernel(
    const float* __restrict__ feat, const int* __restrict__ map,
    float* __restrict__ out) {
  const int b = blockIdx.y;
  const int cell = blockIdx.x * 256 + threadIdx.x;

  const int p = map[b * G_CELLS + cell];

  fv4 row[16];
#pragma unroll
  for (int i = 0; i < 16; ++i) row[i] = (fv4){0.f, 0.f, 0.f, 0.f};

  if (p >= 0) {
    const fv4* r = (const fv4*)feat + (size_t)p * 16; // 256 B row
#pragma unroll
    for (int i = 0; i < 16; ++i) row[i] = r[i];       // consecutive: line-local
  }

  float* o = out + (size_t)b * (G_C * G_CELLS) + cell;
  const float* rowf = (const float*)row;
#pragma unroll
  for (int c = 0; c < G_C; ++c)
    __builtin_nontemporal_store(rowf[c], o + (size_t)c * G_CELLS);
}

extern "C" void kernel_launch(void* const* d_in, const int* in_sizes, int n_in,
                              void* d_out, int out_size, void* d_ws, size_t ws_size,
                              hipStream_t stream) {
  const float* feat = (const float*)d_in[0];   // [P, 64] fp32
  const int* coords = (const int*)d_in[1];     // [P, 4] int32
  float* out = (float*)d_out;                  // [4, 64, 512, 512] fp32

  const int P = in_sizes[0] / G_C;
  int* map = (int*)d_ws; // B*CELLS int32 = 4 MiB

  (void)hipMemsetAsync(map, 0xFF, (size_t)G_B * G_CELLS * sizeof(int), stream);
  ppscatter_map_kernel<<<(P + 255) / 256, 256, 0, stream>>>(coords, map, P);
  ppscatter_gather_kernel<<<dim3(G_CELLS / 256, G_B), 256, 0, stream>>>(
      feat, map, out);
}

// Round 5
// 299.660 us; speedup vs baseline: 1.0336x; 1.0336x over previous
//
#include <hip/hip_runtime.h>

// PointPillarScatter (B=4, C=64, 512x512x1 grid, P=120000)
// Invert scatter -> gather, LDS-staged transpose:
//   1) memset cell->pillar map (d_ws) to -1              (4 MiB)
//   2) scatter: map[b*cells + cell] = p                  (tiny)
//   3) gather: 64 cells/block. Each row loaded by 4 lanes as 4x fv4
//      back-to-back (full 256B line consumption -> 1x fetch), staged into a
//      channel-major LDS tile [64][65], then stored as nontemporal fv4
//      (1 KiB per wave per store instruction, fully coalesced).

#define G_NX 512
#define G_NY 512
#define G_C 64
#define G_B 4
#define G_CELLS (G_NX * G_NY) // 262144 (nz == 1)
#define TCELLS 64             // cells per gather block

typedef float fv4 __attribute__((ext_vector_type(4)));

__global__ __launch_bounds__(256) void ppscatter_map_kernel(
    const int* __restrict__ coords, int* __restrict__ map, int P) {
  int p = blockIdx.x * blockDim.x + threadIdx.x;
  if (p >= P) return;
  int4 cr = ((const int4*)coords)[p]; // [b, z, y, x]
  map[cr.x * G_CELLS + (cr.y + cr.z * G_NX + cr.w)] = p;
}

// grid: (CELLS/64, B), block 256.
__global__ __launch_bounds__(256) void ppscatter_gather_kernel(
    const float* __restrict__ feat, const int* __restrict__ map,
    float* __restrict__ out) {
  __shared__ float lds[G_C][TCELLS + 1]; // channel-major, +1 pad: 16.6 KB

  const int b = blockIdx.y;
  const int cell0 = blockIdx.x * TCELLS;
  const int t = threadIdx.x;

  // ---- load phase: 4 lanes per cell, 64 B chunk each ----
  const int j = t >> 2; // local cell 0..63
  const int q = t & 3;  // row quarter 0..3 (channels 16q..16q+15)
  const int p = map[b * G_CELLS + cell0 + j];

  fv4 ch[4];
  if (p >= 0) {
    const fv4* r = (const fv4*)feat + (size_t)p * 16 + q * 4;
#pragma unroll
    for (int i = 0; i < 4; ++i) ch[i] = r[i]; // back-to-back: full line use
  } else {
#pragma unroll
    for (int i = 0; i < 4; ++i) ch[i] = (fv4){0.f, 0.f, 0.f, 0.f};
  }

#pragma unroll
  for (int i = 0; i < 4; ++i) {
    const int c = q * 16 + i * 4;
    lds[c + 0][j] = ch[i].x; // bank = (16q+4i+k+j)%32 -> 2-way max (free)
    lds[c + 1][j] = ch[i].y;
    lds[c + 2][j] = ch[i].z;
    lds[c + 3][j] = ch[i].w;
  }
  __syncthreads();

  // ---- store phase: lane covers 4 cells of one channel per iteration ----
  const int cell4 = (t & 15) * 4; // 0,4,...,60
  const int coff = t >> 4;        // 0..15
  float* o = out + (size_t)b * (G_C * G_CELLS) + cell0 + cell4;
#pragma unroll
  for (int cc = 0; cc < 4; ++cc) {
    const int c = cc * 16 + coff;
    fv4 v = *(const fv4*)&lds[c][cell4]; // ds_read_b128, near-conflict-free
    __builtin_nontemporal_store(v, (fv4*)(o + (size_t)c * G_CELLS));
  }
}

extern "C" void kernel_launch(void* const* d_in, const int* in_sizes, int n_in,
                              void* d_out, int out_size, void* d_ws, size_t ws_size,
                              hipStream_t stream) {
  const float* feat = (const float*)d_in[0];   // [P, 64] fp32
  const int* coords = (const int*)d_in[1];     // [P, 4] int32
  float* out = (float*)d_out;                  // [4, 64, 512, 512] fp32

  const int P = in_sizes[0] / G_C;
  int* map = (int*)d_ws; // B*CELLS int32 = 4 MiB

  (void)hipMemsetAsync(map, 0xFF, (size_t)G_B * G_CELLS * sizeof(int), stream);
  ppscatter_map_kernel<<<(P + 255) / 256, 256, 0, stream>>>(coords, map, P);
  ppscatter_gather_kernel<<<dim3(G_CELLS / TCELLS, G_B), 256, 0, stream>>>(
      feat, map, out);
}